// Round 2
// baseline (8256.834 us; speedup 1.0000x reference)
//
#include <hip/hip_runtime.h>
#include <hip/hip_cooperative_groups.h>

namespace cg = cooperative_groups;

typedef unsigned int u32;
typedef unsigned long long u64;
typedef unsigned char u8;

static constexpr int SORTN = 131072;   // pow2 >= max chosen count (<= N = 100000)
static constexpr int STILE = 2048;     // bitonic LDS tile (16 KiB of u64)
static constexpr int MAXGR = 64;       // grid-mode round cap
static constexpr u32 FINISH_T = 8192;  // switch to single-block finish below this
static constexpr int MBLK  = 1024;     // match kernel blocks (4/CU with 512 thr)
static constexpr int MTHR  = 512;

// monotonic float->uint mapping (ascending)
__device__ __forceinline__ u32 ordf(float f) {
  u32 u = __float_as_uint(f);
  return (u & 0x80000000u) ? ~u : (u | 0x80000000u);
}
__device__ __forceinline__ float inv_ordf(u32 m) {
  return __uint_as_float((m & 0x80000000u) ? (m ^ 0x80000000u) : ~m);
}

__global__ __launch_bounds__(256)
void k_init(u32* m_ord, double* ssum, u8* matched, u64* node_min,
            float* scoreC, u64* sortbuf, u32* flags, u32* scalars, int N) {
  int i = blockIdx.x * blockDim.x + threadIdx.x;
  if (i < N) {
    m_ord[i] = 0u; ssum[i] = 0.0; matched[i] = 0;
    node_min[i] = ~0ull; node_min[(size_t)N + i] = ~0ull;
    scoreC[i] = 1.0f;   // singleton clusters keep score 1.0
  }
  if (i < SORTN) sortbuf[i] = ~0ull;  // padding sorts to the end
  if (i < 256)   flags[i] = 0u;
  if (i < 16)    scalars[i] = 0u;
}

// wave-per-node dual dot product: s_src = x.W[:256], s_dst = x.W[256:]
__global__ __launch_bounds__(256)
void k_dots(const float4* __restrict__ x4, const float4* __restrict__ W4,
            float* __restrict__ s_src, float* __restrict__ s_dst, int N) {
  int gt = blockIdx.x * blockDim.x + threadIdx.x;
  int w = gt >> 6, lane = gt & 63;
  if (w >= N) return;
  float4 xa = x4[(size_t)w * 64 + lane];
  float4 wa = W4[lane];
  float4 wb = W4[64 + lane];
  float pa = xa.x*wa.x + xa.y*wa.y + xa.z*wa.z + xa.w*wa.w;
  float pb = xa.x*wb.x + xa.y*wb.y + xa.z*wb.z + xa.w*wb.w;
  #pragma unroll
  for (int m = 32; m >= 1; m >>= 1) {
    pa += __shfl_xor(pa, m);
    pb += __shfl_xor(pb, m);
  }
  if (lane == 0) { s_src[w] = pa; s_dst[w] = pb; }
}

// segment max over dst (exact, via ordered-uint atomicMax)
__global__ __launch_bounds__(256)
void k_max(const int* __restrict__ src, const int* __restrict__ dst,
           const float* __restrict__ s_src, const float* __restrict__ s_dst,
           const float* __restrict__ bvec, u32* m_ord, int E) {
  int e = blockIdx.x * blockDim.x + threadIdx.x;
  if (e >= E) return;
  int d = dst[e];
  float r = s_src[src[e]] + s_dst[d] + bvec[0];
  atomicMax(&m_ord[d], ordf(r));
}

// exp(raw - max), f64 segment-sum (deterministic to f32 rounding)
__global__ __launch_bounds__(256)
void k_expsum(const int* __restrict__ src, const int* __restrict__ dst,
              const float* __restrict__ s_src, const float* __restrict__ s_dst,
              const float* __restrict__ bvec, const u32* __restrict__ m_ord,
              float* __restrict__ exb, double* ssum, int E) {
  int e = blockIdx.x * blockDim.x + threadIdx.x;
  if (e >= E) return;
  int d = dst[e];
  float r = s_src[src[e]] + s_dst[d] + bvec[0];
  float m = inv_ordf(m_ord[d]);
  float ex = expf(r - m);
  exb[e] = ex;
  atomicAdd(&ssum[d], (double)ex);
}

// score = softmax + 0.5; frontier entry = (~ord(score))<<32 | edge_id
// (ascending u64 order == descending score with stable index tiebreak)
__global__ __launch_bounds__(256)
void k_scorekey(const int* __restrict__ dst, const float* __restrict__ exb,
                const double* __restrict__ ssum, float* __restrict__ esc,
                u64* __restrict__ front0, int E) {
  int e = blockIdx.x * blockDim.x + threadIdx.x;
  if (e >= E) return;
  float s = (float)ssum[dst[e]];
  float p = exb[e] / s;
  float es = p + 0.5f;
  esc[e] = es;
  front0[e] = ((u64)(~ordf(es)) << 32) | (u32)e;
}

// locally-dominant matching with frontier compaction.
// invariant: edge alive <=> !matched[src] && !matched[dst]; frontier is a
// superset of alive edges, filtered each round during the min phase.
__global__ __launch_bounds__(MTHR, 8)
void k_match(const int* __restrict__ src, const int* __restrict__ dst,
             u64* front0, u64* front1, u8* matched,
             u64* node_min, u64* sortbuf, u32* fcnt, u32* scalars,
             int N, int E) {
  cg::grid_group g = cg::this_grid();
  __shared__ u32 sh_cnt;
  const int tid = blockIdx.x * blockDim.x + threadIdx.x;
  const int nth = gridDim.x * blockDim.x;
  u64* fin = front0; u64* fout = front1;
  int cur = 0;
  u32 cnt = (u32)E;
  for (int r = 0; r < MAXGR; ++r) {
    u64* nm  = node_min + (size_t)cur * N;
    u64* nmn = node_min + (size_t)(cur ^ 1) * N;
    // phase 1: drop dead edges, atomicMin at endpoints, compact survivors
    for (u32 i = tid; i < cnt; i += nth) {
      u64 k = fin[i];
      u32 e = (u32)k;
      int s = src[e], d = dst[e];
      if (matched[s] | matched[d]) continue;
      atomicMin(&nm[s], k);
      if (d != s) atomicMin(&nm[d], k);
      u64 mask = __ballot(1);
      int lane = threadIdx.x & 63;
      int pre = __popcll(mask & ((1ull << lane) - 1ull));
      int ldr = __ffsll((long long)mask) - 1;
      u32 base = 0;
      if (lane == ldr) base = atomicAdd(&fcnt[r], (u32)__popcll(mask));
      base = __shfl(base, ldr);
      fout[base + pre] = k;
    }
    // reset the other node_min buffer for next round (overlaps phase 1)
    for (int v = tid; v < N; v += nth) nmn[v] = ~0ull;
    __threadfence();
    g.sync();
    if (threadIdx.x == 0) sh_cnt = atomicOr(&fcnt[r], 0u);
    __syncthreads();
    u32 ncnt = sh_cnt;
    __syncthreads();
    // phase 2: pick edges that are min at BOTH endpoints (keys unique)
    for (u32 i = tid; i < ncnt; i += nth) {
      u64 k = fout[i];
      u32 e = (u32)k;
      int s = src[e], d = dst[e];
      if (nm[s] == k && nm[d] == k) {
        matched[s] = 1; matched[d] = 1;
        u32 o = atomicAdd(&scalars[0], 1u);
        sortbuf[o] = k;
      }
    }
    __threadfence();
    g.sync();
    cnt = ncnt;
    { u64* t = fin; fin = fout; fout = t; }
    cur ^= 1;
    if (cnt <= FINISH_T) break;
  }
  if (cnt == 0 || blockIdx.x != 0) return;
  // ---- single-block finish: cheap __syncthreads rounds, touched-only resets
  u64* nm = node_min;   // buffer 0; reset phase clears every entry we will read
  while (cnt > 0) {
    // reset touched node_min entries
    for (u32 i = threadIdx.x; i < cnt; i += blockDim.x) {
      u64 k = fin[i]; u32 e = (u32)k;
      nm[src[e]] = ~0ull; nm[dst[e]] = ~0ull;
    }
    if (threadIdx.x == 0) sh_cnt = 0;
    __syncthreads();
    // min + compact
    for (u32 i = threadIdx.x; i < cnt; i += blockDim.x) {
      u64 k = fin[i]; u32 e = (u32)k;
      int s = src[e], d = dst[e];
      if (matched[s] | matched[d]) continue;
      atomicMin(&nm[s], k);
      if (d != s) atomicMin(&nm[d], k);
      u32 o = atomicAdd(&sh_cnt, 1u);
      fout[o] = k;
    }
    __syncthreads();
    u32 nc2 = sh_cnt;
    // pick
    for (u32 i = threadIdx.x; i < nc2; i += blockDim.x) {
      u64 k = fout[i]; u32 e = (u32)k;
      int s = src[e], d = dst[e];
      if (nm[s] == k && nm[d] == k) {
        matched[s] = 1; matched[d] = 1;
        u32 o = atomicAdd(&scalars[0], 1u);
        sortbuf[o] = k;
      }
    }
    __syncthreads();
    cnt = nc2;
    u64* t = fin; fin = fout; fout = t;
  }
}

// bitonic sort of the first P = next_pow2(num_chosen) slots of sortbuf
// (rest of SORTN is ~0 padding; P computed device-side, uniform)
__global__ __launch_bounds__(256)
void k_sort(u64* buf, const u32* __restrict__ scalars) {
  cg::grid_group g = cg::this_grid();
  __shared__ u64 t[STILE];
  const int b = blockIdx.x;
  const int base = b * STILE;
  const int tidg = blockIdx.x * blockDim.x + threadIdx.x;
  const int nth  = gridDim.x * blockDim.x;
  u32 m = scalars[0];
  int P = STILE;
  while (P < (int)m) P <<= 1;   // P <= SORTN since m <= N < SORTN
  // stage 1: all k <= STILE entirely in LDS (direction from global index)
  if (base < P) {
    for (int i = threadIdx.x; i < STILE; i += 256) t[i] = buf[base + i];
    __syncthreads();
    for (int k = 2; k <= STILE; k <<= 1) {
      for (int j = k >> 1; j > 0; j >>= 1) {
        for (int i = threadIdx.x; i < STILE; i += 256) {
          int p = i ^ j;
          if (p > i) {
            bool dir = (((base + i) & k) == 0);
            u64 a = t[i], c = t[p];
            if ((a > c) == dir) { t[i] = c; t[p] = a; }
          }
        }
        __syncthreads();
      }
    }
    for (int i = threadIdx.x; i < STILE; i += 256) buf[base + i] = t[i];
  }
  __threadfence(); g.sync();
  // stages k > STILE: global passes for j >= STILE, LDS finish for j < STILE
  for (int k = STILE << 1; k <= P; k <<= 1) {
    for (int j = k >> 1; j >= STILE; j >>= 1) {
      for (int i = tidg; i < P; i += nth) {
        int p = i ^ j;
        if (p > i) {
          bool dir = ((i & k) == 0);
          u64 a = buf[i], c = buf[p];
          if ((a > c) == dir) { buf[i] = c; buf[p] = a; }
        }
      }
      __threadfence(); g.sync();
    }
    if (base < P) {
      for (int i = threadIdx.x; i < STILE; i += 256) t[i] = buf[base + i];
      __syncthreads();
      bool dir = ((base & k) == 0);  // uniform per tile (k > STILE)
      for (int j = STILE >> 1; j > 0; j >>= 1) {
        for (int i = threadIdx.x; i < STILE; i += 256) {
          int p = i ^ j;
          if (p > i) {
            u64 a = t[i], c = t[p];
            if ((a > c) == dir) { t[i] = c; t[p] = a; }
          }
        }
        __syncthreads();
      }
      for (int i = threadIdx.x; i < STILE; i += 256) buf[base + i] = t[i];
    }
    __threadfence(); g.sync();
  }
}

// sorted position i == cluster id of chosen edge
__global__ __launch_bounds__(256)
void k_assign(const u64* __restrict__ buf, const int* __restrict__ src,
              const int* __restrict__ dst, const float* __restrict__ esc,
              int* cluster, int* memA, int* memB, float* scoreC,
              const u32* __restrict__ scalars) {
  int i = blockIdx.x * blockDim.x + threadIdx.x;
  if (i >= (int)scalars[0]) return;
  u64 k = buf[i];
  u32 e = (u32)(k & 0xffffffffull);
  int s = src[e], d = dst[e];
  cluster[s] = i; cluster[d] = i;
  scoreC[i] = esc[e];
  memA[i] = s;
  memB[i] = (s == d) ? -1 : d;   // self-loop: single member
}

// exclusive scan of unmatched nodes -> trailing singleton cluster ids
__global__ __launch_bounds__(256)
void k_scan1(const u8* __restrict__ matched, u32* partials, int N) {
  __shared__ u32 sh[256];
  int b = blockIdx.x, tx = threadIdx.x;
  int v0 = b * 1024 + tx * 4;
  u32 c = 0;
  #pragma unroll
  for (int q = 0; q < 4; q++) { int v = v0 + q; if (v < N && !matched[v]) c++; }
  sh[tx] = c; __syncthreads();
  for (int s = 128; s > 0; s >>= 1) { if (tx < s) sh[tx] += sh[tx + s]; __syncthreads(); }
  if (tx == 0) partials[b] = sh[0];
}

__global__ void k_scan2(const u32* partials, u32* partials2, u32* scalars, int NB) {
  if (blockIdx.x == 0 && threadIdx.x == 0) {
    u32 run = 0;
    for (int i = 0; i < NB; i++) { partials2[i] = run; run += partials[i]; }
    scalars[1] = run;                 // total unmatched
    scalars[2] = scalars[0] + run;    // num_clusters
  }
}

__global__ __launch_bounds__(256)
void k_scan3(const u8* __restrict__ matched, const u32* __restrict__ partials2,
             const u32* __restrict__ scalars, int* cluster, int* memA, int* memB, int N) {
  __shared__ u32 sh[256];
  int b = blockIdx.x, tx = threadIdx.x;
  int v0 = b * 1024 + tx * 4;
  u32 f[4]; u32 c = 0;
  #pragma unroll
  for (int q = 0; q < 4; q++) { int v = v0 + q; f[q] = (v < N && !matched[v]); c += f[q]; }
  sh[tx] = c; __syncthreads();
  for (int s = 1; s < 256; s <<= 1) {      // Hillis-Steele inclusive scan
    u32 x = sh[tx];
    u32 y = (tx >= s) ? sh[tx - s] : 0;
    __syncthreads();
    sh[tx] = x + y;
    __syncthreads();
  }
  u32 base = scalars[0] + partials2[b] + (sh[tx] - c);
  #pragma unroll
  for (int q = 0; q < 4; q++) {
    if (f[q]) {
      int v = v0 + q;
      int cc = (int)base++;
      cluster[v] = cc; memA[cc] = v; memB[cc] = -1;
    }
  }
}

// new_x: wave per output row; <=2 members per cluster; zero tail rows
__global__ __launch_bounds__(256)
void k_newx(const float4* __restrict__ x4, const int* __restrict__ memA,
            const int* __restrict__ memB, const float* __restrict__ scoreC,
            const u32* __restrict__ scalars, float4* __restrict__ out4, int N) {
  int gt = blockIdx.x * blockDim.x + threadIdx.x;
  int w = gt >> 6, lane = gt & 63;
  if (w >= N) return;
  int nc = (int)scalars[2];
  float4 o;
  if (w < nc) {
    int a = memA[w], b = memB[w];
    float s = scoreC[w];
    float4 va = x4[(size_t)a * 64 + lane];
    float ox = va.x, oy = va.y, oz = va.z, ow = va.w;
    if (b >= 0) {
      float4 vb = x4[(size_t)b * 64 + lane];
      ox += vb.x; oy += vb.y; oz += vb.z; ow += vb.w;
    }
    o = make_float4(ox * s, oy * s, oz * s, ow * s);
  } else {
    o = make_float4(0.f, 0.f, 0.f, 0.f);
  }
  out4[(size_t)w * 64 + lane] = o;
}

__global__ __launch_bounds__(256)
void k_remap(const int* __restrict__ ei, const int* __restrict__ cluster,
             float* __restrict__ outE, int twoE) {
  int i = blockIdx.x * blockDim.x + threadIdx.x;
  if (i < twoE) outE[i] = (float)cluster[ei[i]];
}

__global__ __launch_bounds__(256)
void k_tail(float* __restrict__ outB, const u32* __restrict__ scalars, int N) {
  int i = blockIdx.x * blockDim.x + threadIdx.x;
  if (i < N) outB[i] = 0.0f;                  // batch is all zeros
  if (i == 0) outB[N] = (float)scalars[2];    // num_clusters
}

extern "C" void kernel_launch(void* const* d_in, const int* in_sizes, int n_in,
                              void* d_out, int out_size, void* d_ws, size_t ws_size,
                              hipStream_t stream) {
  const float* x    = (const float*)d_in[0];
  const int*   ei   = (const int*)d_in[1];
  const float* W    = (const float*)d_in[3];
  const float* bvec = (const float*)d_in[4];
  int N = in_sizes[2];
  int E = in_sizes[1] / 2;

  // workspace carve-out (~45 MB)
  char* p = (char*)d_ws;
  auto alloc = [&](size_t bytes) { char* r = p; p += (bytes + 255) & ~(size_t)255; return r; };
  float*  s_src    = (float*)alloc((size_t)N * 4);
  float*  s_dst    = (float*)alloc((size_t)N * 4);
  u32*    m_ord    = (u32*)alloc((size_t)N * 4);
  double* ssum     = (double*)alloc((size_t)N * 8);
  float*  exb      = (float*)alloc((size_t)E * 4);
  float*  esc      = (float*)alloc((size_t)E * 4);
  u64*    front0   = (u64*)alloc((size_t)E * 8);
  u64*    front1   = (u64*)alloc((size_t)E * 8);
  u8*     matched  = (u8*)alloc((size_t)N);
  u64*    node_min = (u64*)alloc((size_t)2 * N * 8);
  u64*    sortbuf  = (u64*)alloc((size_t)SORTN * 8);
  int*    cluster  = (int*)alloc((size_t)N * 4);
  int*    memA     = (int*)alloc((size_t)N * 4);
  int*    memB     = (int*)alloc((size_t)N * 4);
  float*  scoreC   = (float*)alloc((size_t)N * 4);
  u32*    flags    = (u32*)alloc(1024);
  u32*    partials = (u32*)alloc(4096);
  u32*    partials2= (u32*)alloc(4096);
  u32*    scalars  = (u32*)alloc(256);
  (void)ws_size; (void)out_size; (void)n_in;

  const int* srcp = ei;
  const int* dstp = ei + E;
  float* out  = (float*)d_out;
  float* outX = out;
  float* outE = out + (size_t)N * 256;
  float* outB = outE + (size_t)2 * E;

  int cover = (N > SORTN) ? N : SORTN;
  k_init<<<(cover + 255) / 256, 256, 0, stream>>>(m_ord, ssum, matched, node_min,
                                                  scoreC, sortbuf, flags, scalars, N);
  k_dots<<<((size_t)N * 64 + 255) / 256, 256, 0, stream>>>(
      (const float4*)x, (const float4*)W, s_src, s_dst, N);
  k_max<<<(E + 255) / 256, 256, 0, stream>>>(srcp, dstp, s_src, s_dst, bvec, m_ord, E);
  k_expsum<<<(E + 255) / 256, 256, 0, stream>>>(srcp, dstp, s_src, s_dst, bvec, m_ord,
                                                exb, ssum, E);
  k_scorekey<<<(E + 255) / 256, 256, 0, stream>>>(dstp, exb, ssum, esc, front0, E);

  {
    void* args[] = { (void*)&srcp, (void*)&dstp, (void*)&front0, (void*)&front1,
                     (void*)&matched, (void*)&node_min, (void*)&sortbuf,
                     (void*)&flags, (void*)&scalars, (void*)&N, (void*)&E };
    hipLaunchCooperativeKernel((const void*)k_match, dim3(MBLK), dim3(MTHR), args, 0, stream);
  }
  {
    void* args[] = { (void*)&sortbuf, (void*)&scalars };
    hipLaunchCooperativeKernel((const void*)k_sort, dim3(SORTN / STILE), dim3(256), args, 0, stream);
  }

  k_assign<<<SORTN / 256, 256, 0, stream>>>(sortbuf, srcp, dstp, esc,
                                            cluster, memA, memB, scoreC, scalars);
  int NB = (N + 1023) / 1024;
  k_scan1<<<NB, 256, 0, stream>>>(matched, partials, N);
  k_scan2<<<1, 64, 0, stream>>>(partials, partials2, scalars, NB);
  k_scan3<<<NB, 256, 0, stream>>>(matched, partials2, scalars, cluster, memA, memB, N);

  k_newx<<<((size_t)N * 64 + 255) / 256, 256, 0, stream>>>(
      (const float4*)x, memA, memB, scoreC, scalars, (float4*)outX, N);
  k_remap<<<(2 * E + 255) / 256, 256, 0, stream>>>(ei, cluster, outE, 2 * E);
  k_tail<<<(N + 255) / 256, 256, 0, stream>>>(outB, scalars, N);
}

// Round 3
// 2844.751 us; speedup vs baseline: 2.9025x; 2.9025x over previous
//
#include <hip/hip_runtime.h>
#include <hip/hip_cooperative_groups.h>

namespace cg = cooperative_groups;

typedef unsigned int u32;
typedef unsigned long long u64;
typedef unsigned char u8;

static constexpr int SORTN   = 131072; // pow2 >= max chosen count (<= N = 100000)
static constexpr int STILE   = 2048;   // bitonic LDS tile (16 KiB of u64)
static constexpr int NROUNDS = 10;     // fixed grid rounds (kernel-launch coherence)

// monotonic float->uint mapping (ascending)
__device__ __forceinline__ u32 ordf(float f) {
  u32 u = __float_as_uint(f);
  return (u & 0x80000000u) ? ~u : (u | 0x80000000u);
}
__device__ __forceinline__ float inv_ordf(u32 m) {
  return __uint_as_float((m & 0x80000000u) ? (m ^ 0x80000000u) : ~m);
}

// softmax(dst-segment) + 0.5, recomputed identically everywhere it's needed
__device__ __forceinline__ float edge_score(int s, int d,
    const float* __restrict__ s_src, const float* __restrict__ s_dst,
    float bias, const u32* __restrict__ m_ord, const double* __restrict__ ssum) {
  float r = s_src[s] + s_dst[d] + bias;
  float m = inv_ordf(m_ord[d]);
  float ex = expf(r - m);
  return ex / (float)ssum[d] + 0.5f;
}

__global__ __launch_bounds__(256)
void k_init(u32* m_ord, double* ssum, u8* matched, u64* node_min,
            float* scoreC, u64* sortbuf, u32* fcnt, u32* scalars, int N, int E) {
  int i = blockIdx.x * blockDim.x + threadIdx.x;
  if (i < N) {
    m_ord[i] = 0u; ssum[i] = 0.0; matched[i] = 0;
    node_min[i] = ~0ull; node_min[(size_t)N + i] = ~0ull;
    scoreC[i] = 1.0f;   // singleton clusters keep score 1.0
  }
  if (i < SORTN) sortbuf[i] = ~0ull;  // padding sorts to the end
  if (i < 256)   fcnt[i] = 0u;
  if (i < 16)    scalars[i] = 0u;
  if (i == 0)    fcnt[0] = (u32)E;    // frontier 0 = all edges
}

// wave-per-node dual dot product: s_src = x.W[:256], s_dst = x.W[256:]
__global__ __launch_bounds__(256)
void k_dots(const float4* __restrict__ x4, const float4* __restrict__ W4,
            float* __restrict__ s_src, float* __restrict__ s_dst, int N) {
  int gt = blockIdx.x * blockDim.x + threadIdx.x;
  int w = gt >> 6, lane = gt & 63;
  if (w >= N) return;
  float4 xa = x4[(size_t)w * 64 + lane];
  float4 wa = W4[lane];
  float4 wb = W4[64 + lane];
  float pa = xa.x*wa.x + xa.y*wa.y + xa.z*wa.z + xa.w*wa.w;
  float pb = xa.x*wb.x + xa.y*wb.y + xa.z*wb.z + xa.w*wb.w;
  #pragma unroll
  for (int m = 32; m >= 1; m >>= 1) {
    pa += __shfl_xor(pa, m);
    pb += __shfl_xor(pb, m);
  }
  if (lane == 0) { s_src[w] = pa; s_dst[w] = pb; }
}

// segment max over dst (exact, via ordered-uint atomicMax)
__global__ __launch_bounds__(256)
void k_max(const int* __restrict__ src, const int* __restrict__ dst,
           const float* __restrict__ s_src, const float* __restrict__ s_dst,
           const float* __restrict__ bvec, u32* m_ord, int E) {
  int e = blockIdx.x * blockDim.x + threadIdx.x;
  if (e >= E) return;
  int d = dst[e];
  float r = s_src[src[e]] + s_dst[d] + bvec[0];
  atomicMax(&m_ord[d], ordf(r));
}

// exp(raw - max), f64 segment-sum (deterministic to f32 rounding)
__global__ __launch_bounds__(256)
void k_expsum(const int* __restrict__ src, const int* __restrict__ dst,
              const float* __restrict__ s_src, const float* __restrict__ s_dst,
              const float* __restrict__ bvec, const u32* __restrict__ m_ord,
              double* ssum, int E) {
  int e = blockIdx.x * blockDim.x + threadIdx.x;
  if (e >= E) return;
  int d = dst[e];
  float r = s_src[src[e]] + s_dst[d] + bvec[0];
  float ex = expf(r - inv_ordf(m_ord[d]));
  atomicAdd(&ssum[d], (double)ex);
}

// frontier key = (~ord(score))<<32 | edge_id ; sd[e] = (src<<32)|dst
__global__ __launch_bounds__(256)
void k_scorekey(const int* __restrict__ src, const int* __restrict__ dst,
                const float* __restrict__ s_src, const float* __restrict__ s_dst,
                const float* __restrict__ bvec, const u32* __restrict__ m_ord,
                const double* __restrict__ ssum,
                u64* __restrict__ key0, u64* __restrict__ sd, int E) {
  int e = blockIdx.x * blockDim.x + threadIdx.x;
  if (e >= E) return;
  int s = src[e], d = dst[e];
  float es = edge_score(s, d, s_src, s_dst, bvec[0], m_ord, ssum);
  key0[e] = ((u64)(~ordf(es)) << 32) | (u32)e;
  sd[e]   = ((u64)(u32)s << 32) | (u32)d;
}

// one matching round, min phase: filter dead (coherent: previous launch wrote
// matched), atomicMin keys at endpoints; also reset the other nm buffer.
__global__ __launch_bounds__(256)
void k_mmin(const u64* __restrict__ fin, const u32* __restrict__ cntp,
            const u64* __restrict__ sd, const u8* __restrict__ matched,
            u64* nm, u64* nmReset, int N) {
  u32 gid = blockIdx.x * 256 + threadIdx.x;
  if (gid < (u32)N) nmReset[gid] = ~0ull;   // prepare next round's buffer
  u32 cnt = *cntp;
  if (gid >= cnt) return;
  u64 k = fin[gid];
  u64 p = sd[(u32)k];
  int s = (int)(p >> 32), d = (int)(u32)p;
  if (matched[s] | matched[d]) return;
  atomicMin(&nm[s], k);
  if (d != s) atomicMin(&nm[d], k);
}

// pick phase: key min at BOTH endpoints -> matched (vertex-disjoint since keys
// unique); survivors compacted (block-aggregated count, 1 atomic per block).
__global__ __launch_bounds__(256)
void k_mpick(const u64* __restrict__ fin, const u32* __restrict__ cntp,
             const u64* __restrict__ sd, const u64* __restrict__ nm,
             u8* matched, u64* fout, u32* cntOut, u64* sortbuf, u32* scalars) {
  u32 cnt = *cntp;
  if (blockIdx.x * 256u >= cnt) return;   // uniform early-out (before any sync)
  int tx = threadIdx.x, lane = tx & 63, wid = tx >> 6;
  u32 gid = blockIdx.x * 256 + tx;
  u64 k = 0; int s = 0, d = 0;
  bool pk = false, surv = false;
  if (gid < cnt) {
    k = fin[gid];
    u64 p = sd[(u32)k];
    s = (int)(p >> 32); d = (int)(u32)p;
    if (!(matched[s] | matched[d])) {
      if (nm[s] == k && nm[d] == k) pk = true; else surv = true;
    }
  }
  // picks: wave-aggregated append to sortbuf (order fixed by later sort)
  u64 pm = __ballot(pk);
  if (pm) {
    u32 pre = __popcll(pm & ((1ull << lane) - 1ull));
    int ldr = __ffsll((long long)pm) - 1;
    u32 base = 0;
    if (lane == ldr) base = atomicAdd(&scalars[0], (u32)__popcll(pm));
    base = __shfl(base, ldr);
    if (pk) { matched[s] = 1; matched[d] = 1; sortbuf[base + pre] = k; }
  }
  // survivors: block-aggregated compaction
  __shared__ u32 wb[4];
  __shared__ u32 bbase;
  u64 sm = __ballot(surv);
  if (lane == 0) wb[wid] = (u32)__popcll(sm);
  __syncthreads();
  if (tx == 0) {
    u32 t = wb[0] + wb[1] + wb[2] + wb[3];
    bbase = t ? atomicAdd(cntOut, t) : 0u;
  }
  __syncthreads();
  if (surv) {
    u32 woff = 0;
    for (int w = 0; w < wid; w++) woff += wb[w];
    u32 pre = __popcll(sm & ((1ull << lane) - 1ull));
    fout[bbase + woff + pre] = k;
  }
}

// single-block finish: __syncthreads rounds, touched-only nm resets.
// __threadfence between phases -> buffer_inv (L1 could serve stale lines
// written by L2-level atomics otherwise).
__global__ __launch_bounds__(1024)
void k_mfinish(const u64* __restrict__ sd, u64* fA, u64* fB,
               u8* matched, u64* nm, u64* sortbuf,
               const u32* __restrict__ cntp, u32* scalars) {
  __shared__ u32 sh_cnt;
  u32 cnt = *cntp;
  int tx = threadIdx.x;
  u64* fin = fA; u64* fout = fB;   // NROUNDS even -> frontier parity 0
  while (cnt > 0) {
    for (u32 i = tx; i < cnt; i += 1024) {
      u64 p = sd[(u32)fin[i]];
      nm[p >> 32] = ~0ull; nm[(u32)p] = ~0ull;
    }
    if (tx == 0) sh_cnt = 0;
    __threadfence(); __syncthreads();
    for (u32 i = tx; i < cnt; i += 1024) {
      u64 k = fin[i]; u64 p = sd[(u32)k];
      int s = (int)(p >> 32), d = (int)(u32)p;
      if (matched[s] | matched[d]) continue;
      atomicMin(&nm[s], k);
      if (d != s) atomicMin(&nm[d], k);
    }
    __threadfence(); __syncthreads();
    for (u32 i = tx; i < cnt; i += 1024) {
      u64 k = fin[i]; u64 p = sd[(u32)k];
      int s = (int)(p >> 32), d = (int)(u32)p;
      if (matched[s] | matched[d]) continue;
      if (nm[s] == k && nm[d] == k) {
        matched[s] = 1; matched[d] = 1;
        u32 o = atomicAdd(&scalars[0], 1u);
        sortbuf[o] = k;
      } else {
        u32 o = atomicAdd(&sh_cnt, 1u);
        fout[o] = k;
      }
    }
    __threadfence(); __syncthreads();
    cnt = sh_cnt;
    u64* t = fin; fin = fout; fout = t;
    __syncthreads();
  }
}

// bitonic sort of the first P = next_pow2(num_chosen) slots of sortbuf
__global__ __launch_bounds__(256)
void k_sort(u64* buf, const u32* __restrict__ scalars) {
  cg::grid_group g = cg::this_grid();
  __shared__ u64 t[STILE];
  const int b = blockIdx.x;
  const int base = b * STILE;
  const int tidg = blockIdx.x * blockDim.x + threadIdx.x;
  const int nth  = gridDim.x * blockDim.x;
  u32 m = scalars[0];
  int P = STILE;
  while (P < (int)m) P <<= 1;   // P <= SORTN since m <= N < SORTN
  if (base < P) {
    for (int i = threadIdx.x; i < STILE; i += 256) t[i] = buf[base + i];
    __syncthreads();
    for (int k = 2; k <= STILE; k <<= 1) {
      for (int j = k >> 1; j > 0; j >>= 1) {
        for (int i = threadIdx.x; i < STILE; i += 256) {
          int p = i ^ j;
          if (p > i) {
            bool dir = (((base + i) & k) == 0);
            u64 a = t[i], c = t[p];
            if ((a > c) == dir) { t[i] = c; t[p] = a; }
          }
        }
        __syncthreads();
      }
    }
    for (int i = threadIdx.x; i < STILE; i += 256) buf[base + i] = t[i];
  }
  __threadfence(); g.sync(); __threadfence();
  for (int k = STILE << 1; k <= P; k <<= 1) {
    for (int j = k >> 1; j >= STILE; j >>= 1) {
      for (int i = tidg; i < P; i += nth) {
        int p = i ^ j;
        if (p > i) {
          bool dir = ((i & k) == 0);
          u64 a = buf[i], c = buf[p];
          if ((a > c) == dir) { buf[i] = c; buf[p] = a; }
        }
      }
      __threadfence(); g.sync(); __threadfence();
    }
    if (base < P) {
      for (int i = threadIdx.x; i < STILE; i += 256) t[i] = buf[base + i];
      __syncthreads();
      bool dir = ((base & k) == 0);  // uniform per tile (k > STILE)
      for (int j = STILE >> 1; j > 0; j >>= 1) {
        for (int i = threadIdx.x; i < STILE; i += 256) {
          int p = i ^ j;
          if (p > i) {
            u64 a = t[i], c = t[p];
            if ((a > c) == dir) { t[i] = c; t[p] = a; }
          }
        }
        __syncthreads();
      }
      for (int i = threadIdx.x; i < STILE; i += 256) buf[base + i] = t[i];
    }
    __threadfence(); g.sync(); __threadfence();
  }
}

// sorted position i == cluster id of chosen edge
__global__ __launch_bounds__(256)
void k_assign(const u64* __restrict__ buf, const u64* __restrict__ sd,
              const float* __restrict__ s_src, const float* __restrict__ s_dst,
              const float* __restrict__ bvec, const u32* __restrict__ m_ord,
              const double* __restrict__ ssum,
              int* cluster, int* memA, int* memB, float* scoreC,
              const u32* __restrict__ scalars) {
  int i = blockIdx.x * blockDim.x + threadIdx.x;
  if (i >= (int)scalars[0]) return;
  u64 k = buf[i];
  u64 p = sd[(u32)k];
  int s = (int)(p >> 32), d = (int)(u32)p;
  cluster[s] = i; cluster[d] = i;
  scoreC[i] = edge_score(s, d, s_src, s_dst, bvec[0], m_ord, ssum);
  memA[i] = s;
  memB[i] = (s == d) ? -1 : d;   // self-loop: single member
}

// exclusive scan of unmatched nodes -> trailing singleton cluster ids
__global__ __launch_bounds__(256)
void k_scan1(const u8* __restrict__ matched, u32* partials, int N) {
  __shared__ u32 sh[256];
  int b = blockIdx.x, tx = threadIdx.x;
  int v0 = b * 1024 + tx * 4;
  u32 c = 0;
  #pragma unroll
  for (int q = 0; q < 4; q++) { int v = v0 + q; if (v < N && !matched[v]) c++; }
  sh[tx] = c; __syncthreads();
  for (int s = 128; s > 0; s >>= 1) { if (tx < s) sh[tx] += sh[tx + s]; __syncthreads(); }
  if (tx == 0) partials[b] = sh[0];
}

__global__ void k_scan2(const u32* partials, u32* partials2, u32* scalars, int NB) {
  if (blockIdx.x == 0 && threadIdx.x == 0) {
    u32 run = 0;
    for (int i = 0; i < NB; i++) { partials2[i] = run; run += partials[i]; }
    scalars[1] = run;                 // total unmatched
    scalars[2] = scalars[0] + run;    // num_clusters
  }
}

__global__ __launch_bounds__(256)
void k_scan3(const u8* __restrict__ matched, const u32* __restrict__ partials2,
             const u32* __restrict__ scalars, int* cluster, int* memA, int* memB, int N) {
  __shared__ u32 sh[256];
  int b = blockIdx.x, tx = threadIdx.x;
  int v0 = b * 1024 + tx * 4;
  u32 f[4]; u32 c = 0;
  #pragma unroll
  for (int q = 0; q < 4; q++) { int v = v0 + q; f[q] = (v < N && !matched[v]); c += f[q]; }
  sh[tx] = c; __syncthreads();
  for (int s = 1; s < 256; s <<= 1) {      // Hillis-Steele inclusive scan
    u32 x = sh[tx];
    u32 y = (tx >= s) ? sh[tx - s] : 0;
    __syncthreads();
    sh[tx] = x + y;
    __syncthreads();
  }
  u32 base = scalars[0] + partials2[b] + (sh[tx] - c);
  #pragma unroll
  for (int q = 0; q < 4; q++) {
    if (f[q]) {
      int v = v0 + q;
      int cc = (int)base++;
      cluster[v] = cc; memA[cc] = v; memB[cc] = -1;
    }
  }
}

// new_x: wave per output row; <=2 members per cluster; zero tail rows
__global__ __launch_bounds__(256)
void k_newx(const float4* __restrict__ x4, const int* __restrict__ memA,
            const int* __restrict__ memB, const float* __restrict__ scoreC,
            const u32* __restrict__ scalars, float4* __restrict__ out4, int N) {
  int gt = blockIdx.x * blockDim.x + threadIdx.x;
  int w = gt >> 6, lane = gt & 63;
  if (w >= N) return;
  int nc = (int)scalars[2];
  float4 o;
  if (w < nc) {
    int a = memA[w], b = memB[w];
    float s = scoreC[w];
    float4 va = x4[(size_t)a * 64 + lane];
    float ox = va.x, oy = va.y, oz = va.z, ow = va.w;
    if (b >= 0) {
      float4 vb = x4[(size_t)b * 64 + lane];
      ox += vb.x; oy += vb.y; oz += vb.z; ow += vb.w;
    }
    o = make_float4(ox * s, oy * s, oz * s, ow * s);
  } else {
    o = make_float4(0.f, 0.f, 0.f, 0.f);
  }
  out4[(size_t)w * 64 + lane] = o;
}

__global__ __launch_bounds__(256)
void k_remap(const int* __restrict__ ei, const int* __restrict__ cluster,
             float* __restrict__ outE, int twoE) {
  int i = blockIdx.x * blockDim.x + threadIdx.x;
  if (i < twoE) outE[i] = (float)cluster[ei[i]];
}

__global__ __launch_bounds__(256)
void k_tail(float* __restrict__ outB, const u32* __restrict__ scalars, int N) {
  int i = blockIdx.x * blockDim.x + threadIdx.x;
  if (i < N) outB[i] = 0.0f;                  // batch is all zeros
  if (i == 0) outB[N] = (float)scalars[2];    // num_clusters
}

extern "C" void kernel_launch(void* const* d_in, const int* in_sizes, int n_in,
                              void* d_out, int out_size, void* d_ws, size_t ws_size,
                              hipStream_t stream) {
  const float* x    = (const float*)d_in[0];
  const int*   ei   = (const int*)d_in[1];
  const float* W    = (const float*)d_in[3];
  const float* bvec = (const float*)d_in[4];
  int N = in_sizes[2];
  int E = in_sizes[1] / 2;

  // workspace carve-out (~46 MB)
  char* p = (char*)d_ws;
  auto alloc = [&](size_t bytes) { char* r = p; p += (bytes + 255) & ~(size_t)255; return r; };
  float*  s_src    = (float*)alloc((size_t)N * 4);
  float*  s_dst    = (float*)alloc((size_t)N * 4);
  u32*    m_ord    = (u32*)alloc((size_t)N * 4);
  double* ssum     = (double*)alloc((size_t)N * 8);
  u64*    sd       = (u64*)alloc((size_t)E * 8);
  u64*    key0     = (u64*)alloc((size_t)E * 8);
  u64*    key1     = (u64*)alloc((size_t)E * 8);
  u8*     matched  = (u8*)alloc((size_t)N);
  u64*    node_min = (u64*)alloc((size_t)2 * N * 8);
  u64*    sortbuf  = (u64*)alloc((size_t)SORTN * 8);
  int*    cluster  = (int*)alloc((size_t)N * 4);
  int*    memA     = (int*)alloc((size_t)N * 4);
  int*    memB     = (int*)alloc((size_t)N * 4);
  float*  scoreC   = (float*)alloc((size_t)N * 4);
  u32*    fcnt     = (u32*)alloc(1024);
  u32*    partials = (u32*)alloc(4096);
  u32*    partials2= (u32*)alloc(4096);
  u32*    scalars  = (u32*)alloc(256);
  (void)ws_size; (void)out_size; (void)n_in;

  const int* srcp = ei;
  const int* dstp = ei + E;
  float* out  = (float*)d_out;
  float* outX = out;
  float* outE = out + (size_t)N * 256;
  float* outB = outE + (size_t)2 * E;

  int NB_E = (E + 255) / 256;
  int cover = (N > SORTN) ? N : SORTN;
  k_init<<<(cover + 255) / 256, 256, 0, stream>>>(m_ord, ssum, matched, node_min,
                                                  scoreC, sortbuf, fcnt, scalars, N, E);
  k_dots<<<((size_t)N * 64 + 255) / 256, 256, 0, stream>>>(
      (const float4*)x, (const float4*)W, s_src, s_dst, N);
  k_max<<<NB_E, 256, 0, stream>>>(srcp, dstp, s_src, s_dst, bvec, m_ord, E);
  k_expsum<<<NB_E, 256, 0, stream>>>(srcp, dstp, s_src, s_dst, bvec, m_ord, ssum, E);
  k_scorekey<<<NB_E, 256, 0, stream>>>(srcp, dstp, s_src, s_dst, bvec, m_ord, ssum,
                                       key0, sd, E);

  // matching: fixed round count, kernel boundaries provide coherence
  u64* kb[2] = { key0, key1 };
  for (int r = 0; r < NROUNDS; ++r) {
    u64* fin  = kb[r & 1];
    u64* fout = kb[(r & 1) ^ 1];
    u64* nm   = node_min + (size_t)(r & 1) * N;
    u64* nmR  = node_min + (size_t)((r & 1) ^ 1) * N;
    k_mmin<<<NB_E, 256, 0, stream>>>(fin, fcnt + r, sd, matched, nm, nmR, N);
    k_mpick<<<NB_E, 256, 0, stream>>>(fin, fcnt + r, sd, nm, matched,
                                      fout, fcnt + r + 1, sortbuf, scalars);
  }
  k_mfinish<<<1, 1024, 0, stream>>>(sd, key0, key1, matched, node_min, sortbuf,
                                    fcnt + NROUNDS, scalars);

  {
    void* args[] = { (void*)&sortbuf, (void*)&scalars };
    hipLaunchCooperativeKernel((const void*)k_sort, dim3(SORTN / STILE), dim3(256), args, 0, stream);
  }

  k_assign<<<SORTN / 256, 256, 0, stream>>>(sortbuf, sd, s_src, s_dst, bvec, m_ord,
                                            ssum, cluster, memA, memB, scoreC, scalars);
  int NB = (N + 1023) / 1024;
  k_scan1<<<NB, 256, 0, stream>>>(matched, partials, N);
  k_scan2<<<1, 64, 0, stream>>>(partials, partials2, scalars, NB);
  k_scan3<<<NB, 256, 0, stream>>>(matched, partials2, scalars, cluster, memA, memB, N);

  k_newx<<<((size_t)N * 64 + 255) / 256, 256, 0, stream>>>(
      (const float4*)x, memA, memB, scoreC, scalars, (float4*)outX, N);
  k_remap<<<(2 * E + 255) / 256, 256, 0, stream>>>(ei, cluster, outE, 2 * E);
  k_tail<<<(N + 255) / 256, 256, 0, stream>>>(outB, scalars, N);
}

// Round 4
// 2235.222 us; speedup vs baseline: 3.6940x; 1.2727x over previous
//
#include <hip/hip_runtime.h>

typedef unsigned int u32;
typedef unsigned long long u64;
typedef unsigned char u8;

static constexpr int SORTN   = 65536;  // pow2 >= max chosen pairs (<= N/2 + ~16 selfloops)
static constexpr int STILE   = 2048;   // bitonic LDS tile (2048 x 16B = 32 KiB)
static constexpr int NROUNDS = 10;     // grid round-pairs (kernel-boundary coherence)

// monotonic float->uint mapping (ascending); bijective
__device__ __forceinline__ u32 ordf(float f) {
  u32 u = __float_as_uint(f);
  return (u & 0x80000000u) ? ~u : (u | 0x80000000u);
}
__device__ __forceinline__ float inv_ordf(u32 m) {
  return __uint_as_float((m & 0x80000000u) ? (m ^ 0x80000000u) : ~m);
}

__global__ __launch_bounds__(256)
void k_init(u32* m_ord, double* ssum, u8* matched, u64* node_min,
            float* scoreC, ulonglong2* sortbuf, u32* fcnt, u32* scalars,
            int N, int E) {
  int i = blockIdx.x * blockDim.x + threadIdx.x;
  if (i < N) {
    m_ord[i] = 0u; ssum[i] = 0.0; matched[i] = 0;
    node_min[i] = ~0ull; node_min[(size_t)N + i] = ~0ull;
    scoreC[i] = 1.0f;   // singleton clusters keep score 1.0
  }
  if (i < SORTN) sortbuf[i] = make_ulonglong2(~0ull, ~0ull); // pad sorts to end
  if (i < 256)   fcnt[i] = 0u;
  if (i < 16)    scalars[i] = 0u;
  if (i == 0)    fcnt[0] = (u32)E;    // frontier 0 = all edges
}

// wave-per-node dual dot product: s_src = x.W[:256], s_dst = x.W[256:]
__global__ __launch_bounds__(256)
void k_dots(const float4* __restrict__ x4, const float4* __restrict__ W4,
            float* __restrict__ s_src, float* __restrict__ s_dst, int N) {
  int gt = blockIdx.x * blockDim.x + threadIdx.x;
  int w = gt >> 6, lane = gt & 63;
  if (w >= N) return;
  float4 xa = x4[(size_t)w * 64 + lane];
  float4 wa = W4[lane];
  float4 wb = W4[64 + lane];
  float pa = xa.x*wa.x + xa.y*wa.y + xa.z*wa.z + xa.w*wa.w;
  float pb = xa.x*wb.x + xa.y*wb.y + xa.z*wb.z + xa.w*wb.w;
  #pragma unroll
  for (int m = 32; m >= 1; m >>= 1) {
    pa += __shfl_xor(pa, m);
    pb += __shfl_xor(pb, m);
  }
  if (lane == 0) { s_src[w] = pa; s_dst[w] = pb; }
}

// segment max over dst (exact, via ordered-uint atomicMax)
__global__ __launch_bounds__(256)
void k_max(const int* __restrict__ src, const int* __restrict__ dst,
           const float* __restrict__ s_src, const float* __restrict__ s_dst,
           const float* __restrict__ bvec, u32* m_ord, int E) {
  int e = blockIdx.x * blockDim.x + threadIdx.x;
  if (e >= E) return;
  int d = dst[e];
  float r = s_src[src[e]] + s_dst[d] + bvec[0];
  atomicMax(&m_ord[d], ordf(r));
}

// exp(raw - max), f64 segment-sum (deterministic to f32 rounding)
__global__ __launch_bounds__(256)
void k_expsum(const int* __restrict__ src, const int* __restrict__ dst,
              const float* __restrict__ s_src, const float* __restrict__ s_dst,
              const float* __restrict__ bvec, const u32* __restrict__ m_ord,
              double* ssum, int E) {
  int e = blockIdx.x * blockDim.x + threadIdx.x;
  if (e >= E) return;
  int d = dst[e];
  float r = s_src[src[e]] + s_dst[d] + bvec[0];
  float ex = expf(r - inv_ordf(m_ord[d]));
  atomicAdd(&ssum[d], (double)ex);
}

// frontier entry: .x = key = (~ord(score))<<32 | edge_id  (asc == desc score,
// stable index tiebreak), .y = (src<<32)|dst  -- self-contained, no gathers.
__global__ __launch_bounds__(256)
void k_scorekey(const int* __restrict__ src, const int* __restrict__ dst,
                const float* __restrict__ s_src, const float* __restrict__ s_dst,
                const float* __restrict__ bvec, const u32* __restrict__ m_ord,
                const double* __restrict__ ssum,
                ulonglong2* __restrict__ front0, int E) {
  int e = blockIdx.x * blockDim.x + threadIdx.x;
  if (e >= E) return;
  int s = src[e], d = dst[e];
  float r = s_src[s] + s_dst[d] + bvec[0];
  float ex = expf(r - inv_ordf(m_ord[d]));
  float es = ex / (float)ssum[d] + 0.5f;
  u64 key = ((u64)(~ordf(es)) << 32) | (u32)e;
  u64 sd  = ((u64)(u32)s << 32) | (u32)d;
  front0[e] = make_ulonglong2(key, sd);
}

// matching round, min phase: filter dead, atomicMin key at endpoints
__global__ __launch_bounds__(256)
void k_mmin(const ulonglong2* __restrict__ fin, const u32* __restrict__ cntp,
            const u8* __restrict__ matched, u64* nm) {
  u32 cnt = *cntp;
  u32 nth = gridDim.x * 256;
  for (u32 i = blockIdx.x * 256 + threadIdx.x; i < cnt; i += nth) {
    ulonglong2 t = fin[i];
    int s = (int)(t.y >> 32), d = (int)(u32)t.y;
    if (matched[s] | matched[d]) continue;
    atomicMin(&nm[s], t.x);
    if (d != s) atomicMin(&nm[d], t.x);
  }
}

// pick phase: min at BOTH endpoints -> matched (vertex-disjoint, keys unique);
// survivors compacted (1 atomic/block) + survivor-only reset of next nm buffer.
__global__ __launch_bounds__(256)
void k_mpick(const ulonglong2* __restrict__ fin, const u32* __restrict__ cntp,
             const u64* __restrict__ nm, u64* nmNext, u8* matched,
             ulonglong2* fout, u32* cntOut, ulonglong2* sortbuf, u32* scalars) {
  __shared__ u32 wb[4];
  __shared__ u32 bbase;
  u32 cnt = *cntp;
  int tx = threadIdx.x, lane = tx & 63, wid = tx >> 6;
  for (u32 base = blockIdx.x * 256; base < cnt; base += gridDim.x * 256) {
    u32 gid = base + tx;
    ulonglong2 t = make_ulonglong2(0ull, 0ull);
    int s = 0, d = 0;
    bool pk = false, surv = false;
    if (gid < cnt) {
      t = fin[gid];
      s = (int)(t.y >> 32); d = (int)(u32)t.y;
      if (!(matched[s] | matched[d])) {
        if (nm[s] == t.x && nm[d] == t.x) pk = true; else surv = true;
      }
    }
    // picks: wave-aggregated append (order fixed by later sort)
    u64 pm = __ballot(pk);
    if (pm) {
      u32 pre = (u32)__popcll(pm & ((1ull << lane) - 1ull));
      int ldr = __ffsll((long long)pm) - 1;
      u32 pb = 0;
      if (lane == ldr) pb = atomicAdd(&scalars[0], (u32)__popcll(pm));
      pb = __shfl(pb, ldr);
      if (pk) {
        matched[s] = 1; matched[d] = 1;
        sortbuf[pb + pre] = t;
      }
    }
    // survivors: block-aggregated compaction + nmNext reset (exactly the
    // nodes the next round can touch)
    u64 sm = __ballot(surv);
    if (lane == 0) wb[wid] = (u32)__popcll(sm);
    __syncthreads();
    if (tx == 0) {
      u32 tt = wb[0] + wb[1] + wb[2] + wb[3];
      bbase = tt ? atomicAdd(cntOut, tt) : 0u;
    }
    __syncthreads();
    if (surv) {
      u32 woff = 0;
      for (int w = 0; w < wid; w++) woff += wb[w];
      u32 pre = (u32)__popcll(sm & ((1ull << lane) - 1ull));
      fout[bbase + woff + pre] = t;
      nmNext[s] = ~0ull;
      nmNext[d] = ~0ull;
    }
    __syncthreads();
  }
}

// single-block fence-free finish. The only cross-path hazard is nm (written by
// L2 atomics, read otherwise through L1) -> read it via atomicAdd(p,0) which
// goes to L2. Everything else is same-L1 plain ops ordered by __syncthreads
// (which drains vmcnt). NO __threadfence => no gfx950 L2 writeback/invalidate.
__global__ __launch_bounds__(1024)
void k_mfinish(ulonglong2* fA, ulonglong2* fB, u8* matched, u64* nm,
               ulonglong2* sortbuf, const u32* __restrict__ cntp, u32* scalars) {
  __shared__ u32 sh_cnt;
  u32 cnt = *cntp;
  int tx = threadIdx.x;
  ulonglong2* fin = fA; ulonglong2* fout = fB;
  while (cnt > 0) {
    // reset touched nm entries (plain write-through stores)
    for (u32 i = tx; i < cnt; i += 1024) {
      u64 p = fin[i].y;
      nm[p >> 32] = ~0ull; nm[(u32)p] = ~0ull;
    }
    if (tx == 0) sh_cnt = 0;
    __syncthreads();
    for (u32 i = tx; i < cnt; i += 1024) {
      ulonglong2 t = fin[i];
      int s = (int)(t.y >> 32), d = (int)(u32)t.y;
      if (matched[s] | matched[d]) continue;
      atomicMin(&nm[s], t.x);
      if (d != s) atomicMin(&nm[d], t.x);
    }
    __syncthreads();
    for (u32 i = tx; i < cnt; i += 1024) {
      ulonglong2 t = fin[i];
      int s = (int)(t.y >> 32), d = (int)(u32)t.y;
      if (matched[s] | matched[d]) continue;
      u64 a = atomicAdd(&nm[s], 0ull);            // atomic read (L2-coherent)
      u64 b = (d == s) ? a : atomicAdd(&nm[d], 0ull);
      if (a == t.x && b == t.x) {
        matched[s] = 1; matched[d] = 1;
        u32 o = atomicAdd(&scalars[0], 1u);
        sortbuf[o] = t;
      } else {
        u32 o = atomicAdd(&sh_cnt, 1u);
        fout[o] = t;
      }
    }
    __syncthreads();
    cnt = sh_cnt;
    ulonglong2* tmp = fin; fin = fout; fout = tmp;
    __syncthreads();
  }
}

// ---- bitonic sort of SORTN {key,sd} pairs by .x, as plain launches ----
__global__ __launch_bounds__(256)
void k_sort1(ulonglong2* buf) {
  __shared__ ulonglong2 t[STILE];
  const int base = blockIdx.x * STILE;
  for (int i = threadIdx.x; i < STILE; i += 256) t[i] = buf[base + i];
  __syncthreads();
  for (int k = 2; k <= STILE; k <<= 1) {
    for (int j = k >> 1; j > 0; j >>= 1) {
      for (int i = threadIdx.x; i < STILE; i += 256) {
        int p = i ^ j;
        if (p > i) {
          bool dir = (((base + i) & k) == 0);
          ulonglong2 a = t[i], c = t[p];
          if ((a.x > c.x) == dir) { t[i] = c; t[p] = a; }
        }
      }
      __syncthreads();
    }
  }
  for (int i = threadIdx.x; i < STILE; i += 256) buf[base + i] = t[i];
}

__global__ __launch_bounds__(256)
void k_gpass(ulonglong2* buf, int j, int k) {
  int i = blockIdx.x * 256 + threadIdx.x;
  int p = i ^ j;
  if (p > i && p < SORTN) {
    bool dir = ((i & k) == 0);
    ulonglong2 a = buf[i], c = buf[p];
    if ((a.x > c.x) == dir) { buf[i] = c; buf[p] = a; }
  }
}

__global__ __launch_bounds__(256)
void k_sortl(ulonglong2* buf, int k) {
  __shared__ ulonglong2 t[STILE];
  const int base = blockIdx.x * STILE;
  const bool dir = ((base & k) == 0);   // uniform per tile (k > STILE)
  for (int i = threadIdx.x; i < STILE; i += 256) t[i] = buf[base + i];
  __syncthreads();
  for (int j = STILE >> 1; j > 0; j >>= 1) {
    for (int i = threadIdx.x; i < STILE; i += 256) {
      int p = i ^ j;
      if (p > i) {
        ulonglong2 a = t[i], c = t[p];
        if ((a.x > c.x) == dir) { t[i] = c; t[p] = a; }
      }
    }
    __syncthreads();
  }
  for (int i = threadIdx.x; i < STILE; i += 256) buf[base + i] = t[i];
}

// sorted position i == cluster id; score recovered bit-exactly from the key
__global__ __launch_bounds__(256)
void k_assign(const ulonglong2* __restrict__ buf,
              int* cluster, int* memA, int* memB, float* scoreC,
              const u32* __restrict__ scalars) {
  int i = blockIdx.x * blockDim.x + threadIdx.x;
  if (i >= (int)scalars[0]) return;
  ulonglong2 t = buf[i];
  int s = (int)(t.y >> 32), d = (int)(u32)t.y;
  cluster[s] = i; cluster[d] = i;
  scoreC[i] = inv_ordf(~(u32)(t.x >> 32));
  memA[i] = s;
  memB[i] = (s == d) ? -1 : d;   // self-loop: single member
}

// exclusive scan of unmatched nodes -> trailing singleton cluster ids
__global__ __launch_bounds__(256)
void k_scan1(const u8* __restrict__ matched, u32* partials, int N) {
  __shared__ u32 sh[256];
  int b = blockIdx.x, tx = threadIdx.x;
  int v0 = b * 1024 + tx * 4;
  u32 c = 0;
  #pragma unroll
  for (int q = 0; q < 4; q++) { int v = v0 + q; if (v < N && !matched[v]) c++; }
  sh[tx] = c; __syncthreads();
  for (int s = 128; s > 0; s >>= 1) { if (tx < s) sh[tx] += sh[tx + s]; __syncthreads(); }
  if (tx == 0) partials[b] = sh[0];
}

__global__ void k_scan2(const u32* partials, u32* partials2, u32* scalars, int NB) {
  if (blockIdx.x == 0 && threadIdx.x == 0) {
    u32 run = 0;
    for (int i = 0; i < NB; i++) { partials2[i] = run; run += partials[i]; }
    scalars[1] = run;                 // total unmatched
    scalars[2] = scalars[0] + run;    // num_clusters
  }
}

__global__ __launch_bounds__(256)
void k_scan3(const u8* __restrict__ matched, const u32* __restrict__ partials2,
             const u32* __restrict__ scalars, int* cluster, int* memA, int* memB, int N) {
  __shared__ u32 sh[256];
  int b = blockIdx.x, tx = threadIdx.x;
  int v0 = b * 1024 + tx * 4;
  u32 f[4]; u32 c = 0;
  #pragma unroll
  for (int q = 0; q < 4; q++) { int v = v0 + q; f[q] = (v < N && !matched[v]); c += f[q]; }
  sh[tx] = c; __syncthreads();
  for (int s = 1; s < 256; s <<= 1) {      // Hillis-Steele inclusive scan
    u32 x = sh[tx];
    u32 y = (tx >= s) ? sh[tx - s] : 0;
    __syncthreads();
    sh[tx] = x + y;
    __syncthreads();
  }
  u32 base = scalars[0] + partials2[b] + (sh[tx] - c);
  #pragma unroll
  for (int q = 0; q < 4; q++) {
    if (f[q]) {
      int v = v0 + q;
      int cc = (int)base++;
      cluster[v] = cc; memA[cc] = v; memB[cc] = -1;
    }
  }
}

// new_x: wave per output row; <=2 members per cluster; zero tail rows
__global__ __launch_bounds__(256)
void k_newx(const float4* __restrict__ x4, const int* __restrict__ memA,
            const int* __restrict__ memB, const float* __restrict__ scoreC,
            const u32* __restrict__ scalars, float4* __restrict__ out4, int N) {
  int gt = blockIdx.x * blockDim.x + threadIdx.x;
  int w = gt >> 6, lane = gt & 63;
  if (w >= N) return;
  int nc = (int)scalars[2];
  float4 o;
  if (w < nc) {
    int a = memA[w], b = memB[w];
    float s = scoreC[w];
    float4 va = x4[(size_t)a * 64 + lane];
    float ox = va.x, oy = va.y, oz = va.z, ow = va.w;
    if (b >= 0) {
      float4 vb = x4[(size_t)b * 64 + lane];
      ox += vb.x; oy += vb.y; oz += vb.z; ow += vb.w;
    }
    o = make_float4(ox * s, oy * s, oz * s, ow * s);
  } else {
    o = make_float4(0.f, 0.f, 0.f, 0.f);
  }
  out4[(size_t)w * 64 + lane] = o;
}

__global__ __launch_bounds__(256)
void k_remap(const int* __restrict__ ei, const int* __restrict__ cluster,
             float* __restrict__ outE, int twoE) {
  int i = blockIdx.x * blockDim.x + threadIdx.x;
  if (i < twoE) outE[i] = (float)cluster[ei[i]];
}

__global__ __launch_bounds__(256)
void k_tail(float* __restrict__ outB, const u32* __restrict__ scalars, int N) {
  int i = blockIdx.x * blockDim.x + threadIdx.x;
  if (i < N) outB[i] = 0.0f;                  // batch is all zeros
  if (i == 0) outB[N] = (float)scalars[2];    // num_clusters
}

extern "C" void kernel_launch(void* const* d_in, const int* in_sizes, int n_in,
                              void* d_out, int out_size, void* d_ws, size_t ws_size,
                              hipStream_t stream) {
  const float* x    = (const float*)d_in[0];
  const int*   ei   = (const int*)d_in[1];
  const float* W    = (const float*)d_in[3];
  const float* bvec = (const float*)d_in[4];
  int N = in_sizes[2];
  int E = in_sizes[1] / 2;

  // workspace carve-out (~57 MB)
  char* p = (char*)d_ws;
  auto alloc = [&](size_t bytes) { char* r = p; p += (bytes + 255) & ~(size_t)255; return r; };
  float*      s_src    = (float*)alloc((size_t)N * 4);
  float*      s_dst    = (float*)alloc((size_t)N * 4);
  u32*        m_ord    = (u32*)alloc((size_t)N * 4);
  double*     ssum     = (double*)alloc((size_t)N * 8);
  ulonglong2* frontA   = (ulonglong2*)alloc((size_t)E * 16);
  ulonglong2* frontB   = (ulonglong2*)alloc((size_t)E * 16);
  u8*         matched  = (u8*)alloc((size_t)N);
  u64*        node_min = (u64*)alloc((size_t)2 * N * 8);
  ulonglong2* sortbuf  = (ulonglong2*)alloc((size_t)SORTN * 16);
  int*        cluster  = (int*)alloc((size_t)N * 4);
  int*        memA     = (int*)alloc((size_t)N * 4);
  int*        memB     = (int*)alloc((size_t)N * 4);
  float*      scoreC   = (float*)alloc((size_t)N * 4);
  u32*        fcnt     = (u32*)alloc(1024);
  u32*        partials = (u32*)alloc(4096);
  u32*        partials2= (u32*)alloc(4096);
  u32*        scalars  = (u32*)alloc(256);
  (void)ws_size; (void)out_size; (void)n_in;

  const int* srcp = ei;
  const int* dstp = ei + E;
  float* out  = (float*)d_out;
  float* outX = out;
  float* outE = out + (size_t)N * 256;
  float* outB = outE + (size_t)2 * E;

  int NB_E = (E + 255) / 256;
  int cover = (N > SORTN) ? N : SORTN;
  k_init<<<(cover + 255) / 256, 256, 0, stream>>>(m_ord, ssum, matched, node_min,
                                                  scoreC, sortbuf, fcnt, scalars, N, E);
  k_dots<<<((size_t)N * 64 + 255) / 256, 256, 0, stream>>>(
      (const float4*)x, (const float4*)W, s_src, s_dst, N);
  k_max<<<NB_E, 256, 0, stream>>>(srcp, dstp, s_src, s_dst, bvec, m_ord, E);
  k_expsum<<<NB_E, 256, 0, stream>>>(srcp, dstp, s_src, s_dst, bvec, m_ord, ssum, E);
  k_scorekey<<<NB_E, 256, 0, stream>>>(srcp, dstp, s_src, s_dst, bvec, m_ord, ssum,
                                       frontA, E);

  // matching: fixed rounds, kernel boundaries provide coherence; shrinking grids
  ulonglong2* kb[2] = { frontA, frontB };
  for (int r = 0; r < NROUNDS; ++r) {
    ulonglong2* fin  = kb[r & 1];
    ulonglong2* fout = kb[(r & 1) ^ 1];
    u64* nm  = node_min + (size_t)(r & 1) * N;
    u64* nmN = node_min + (size_t)((r & 1) ^ 1) * N;
    int nbr = NB_E >> r; if (nbr < 48) nbr = 48;
    k_mmin<<<nbr, 256, 0, stream>>>(fin, fcnt + r, matched, nm);
    k_mpick<<<nbr, 256, 0, stream>>>(fin, fcnt + r, nm, nmN, matched,
                                     fout, fcnt + r + 1, sortbuf, scalars);
  }
  k_mfinish<<<1, 1024, 0, stream>>>(frontA, frontB, matched, node_min, sortbuf,
                                    fcnt + NROUNDS, scalars);

  // sort chosen edges (bitonic over SORTN, plain launches)
  k_sort1<<<SORTN / STILE, 256, 0, stream>>>(sortbuf);
  for (int k = STILE << 1; k <= SORTN; k <<= 1) {
    for (int j = k >> 1; j >= STILE; j >>= 1)
      k_gpass<<<SORTN / 256, 256, 0, stream>>>(sortbuf, j, k);
    k_sortl<<<SORTN / STILE, 256, 0, stream>>>(sortbuf, k);
  }

  k_assign<<<SORTN / 256, 256, 0, stream>>>(sortbuf, cluster, memA, memB, scoreC, scalars);
  int NB = (N + 1023) / 1024;
  k_scan1<<<NB, 256, 0, stream>>>(matched, partials, N);
  k_scan2<<<1, 64, 0, stream>>>(partials, partials2, scalars, NB);
  k_scan3<<<NB, 256, 0, stream>>>(matched, partials2, scalars, cluster, memA, memB, N);

  k_newx<<<((size_t)N * 64 + 255) / 256, 256, 0, stream>>>(
      (const float4*)x, memA, memB, scoreC, scalars, (float4*)outX, N);
  k_remap<<<(2 * E + 255) / 256, 256, 0, stream>>>(ei, cluster, outE, 2 * E);
  k_tail<<<(N + 255) / 256, 256, 0, stream>>>(outB, scalars, N);
}

// Round 5
// 1444.078 us; speedup vs baseline: 5.7177x; 1.5479x over previous
//
#include <hip/hip_runtime.h>

typedef unsigned int u32;
typedef unsigned long long u64;
typedef unsigned char u8;

static constexpr int SORTN   = 65536;  // pow2 >= max chosen pairs (<= N/2 + selfloops)
static constexpr int STILE   = 2048;   // bitonic LDS tile (2048 x 16B = 32 KiB)
static constexpr int NROUNDS = 20;     // grid round-pairs (kernel-boundary coherence)

// monotonic float->uint mapping (ascending); bijective
__device__ __forceinline__ u32 ordf(float f) {
  u32 u = __float_as_uint(f);
  return (u & 0x80000000u) ? ~u : (u | 0x80000000u);
}
__device__ __forceinline__ float inv_ordf(u32 m) {
  return __uint_as_float((m & 0x80000000u) ? (m ^ 0x80000000u) : ~m);
}

__global__ __launch_bounds__(256)
void k_init(u32* m_ord, double* ssum, u8* matched, u64* node_min,
            float* scoreC, ulonglong2* sortbuf, u32* fcnt, u32* scalars,
            int N, int E) {
  int i = blockIdx.x * blockDim.x + threadIdx.x;
  if (i < N) {
    m_ord[i] = 0u; ssum[i] = 0.0; matched[i] = 0;
    node_min[i] = ~0ull; node_min[(size_t)N + i] = ~0ull;
    scoreC[i] = 1.0f;   // singleton clusters keep score 1.0
  }
  if (i < SORTN) sortbuf[i] = make_ulonglong2(~0ull, ~0ull); // pad sorts to end
  if (i < 256)   fcnt[i] = 0u;
  if (i < 16)    scalars[i] = 0u;
  if (i == 0)    fcnt[0] = (u32)E;    // frontier 0 = all edges
}

// wave-per-node dual dot product: s_src = x.W[:256], s_dst = x.W[256:]
__global__ __launch_bounds__(256)
void k_dots(const float4* __restrict__ x4, const float4* __restrict__ W4,
            float* __restrict__ s_src, float* __restrict__ s_dst, int N) {
  int gt = blockIdx.x * blockDim.x + threadIdx.x;
  int w = gt >> 6, lane = gt & 63;
  if (w >= N) return;
  float4 xa = x4[(size_t)w * 64 + lane];
  float4 wa = W4[lane];
  float4 wb = W4[64 + lane];
  float pa = xa.x*wa.x + xa.y*wa.y + xa.z*wa.z + xa.w*wa.w;
  float pb = xa.x*wb.x + xa.y*wb.y + xa.z*wb.z + xa.w*wb.w;
  #pragma unroll
  for (int m = 32; m >= 1; m >>= 1) {
    pa += __shfl_xor(pa, m);
    pb += __shfl_xor(pb, m);
  }
  if (lane == 0) { s_src[w] = pa; s_dst[w] = pb; }
}

// segment max over dst (exact, via ordered-uint atomicMax)
__global__ __launch_bounds__(256)
void k_max(const int* __restrict__ src, const int* __restrict__ dst,
           const float* __restrict__ s_src, const float* __restrict__ s_dst,
           const float* __restrict__ bvec, u32* m_ord, int E) {
  int e = blockIdx.x * blockDim.x + threadIdx.x;
  if (e >= E) return;
  int d = dst[e];
  float r = s_src[src[e]] + s_dst[d] + bvec[0];
  atomicMax(&m_ord[d], ordf(r));
}

// exp(raw - max), f64 segment-sum (deterministic to f32 rounding)
__global__ __launch_bounds__(256)
void k_expsum(const int* __restrict__ src, const int* __restrict__ dst,
              const float* __restrict__ s_src, const float* __restrict__ s_dst,
              const float* __restrict__ bvec, const u32* __restrict__ m_ord,
              double* ssum, int E) {
  int e = blockIdx.x * blockDim.x + threadIdx.x;
  if (e >= E) return;
  int d = dst[e];
  float r = s_src[src[e]] + s_dst[d] + bvec[0];
  float ex = expf(r - inv_ordf(m_ord[d]));
  atomicAdd(&ssum[d], (double)ex);
}

// frontier entry: .x = key = (~ord(score))<<32 | edge_id  (asc == desc score,
// stable index tiebreak), .y = (src<<32)|dst  -- self-contained, no gathers.
__global__ __launch_bounds__(256)
void k_scorekey(const int* __restrict__ src, const int* __restrict__ dst,
                const float* __restrict__ s_src, const float* __restrict__ s_dst,
                const float* __restrict__ bvec, const u32* __restrict__ m_ord,
                const double* __restrict__ ssum,
                ulonglong2* __restrict__ front0, int E) {
  int e = blockIdx.x * blockDim.x + threadIdx.x;
  if (e >= E) return;
  int s = src[e], d = dst[e];
  float r = s_src[s] + s_dst[d] + bvec[0];
  float ex = expf(r - inv_ordf(m_ord[d]));
  float es = ex / (float)ssum[d] + 0.5f;
  u64 key = ((u64)(~ordf(es)) << 32) | (u32)e;
  u64 sd  = ((u64)(u32)s << 32) | (u32)d;
  front0[e] = make_ulonglong2(key, sd);
}

// matching round, min phase: filter dead, atomicMin key at endpoints.
// template<R> only to give each round a distinct symbol in the profile.
template<int R>
__global__ __launch_bounds__(256)
void k_mmin(const ulonglong2* __restrict__ fin, const u32* __restrict__ cntp,
            const u8* __restrict__ matched, u64* nm) {
  u32 cnt = *cntp;
  u32 nth = gridDim.x * 256;
  for (u32 i = blockIdx.x * 256 + threadIdx.x; i < cnt; i += nth) {
    ulonglong2 t = fin[i];
    int s = (int)(t.y >> 32), d = (int)(u32)t.y;
    if (matched[s] | matched[d]) continue;
    atomicMin(&nm[s], t.x);
    if (d != s) atomicMin(&nm[d], t.x);
  }
}

// pick phase: min at BOTH endpoints -> matched (vertex-disjoint, keys unique);
// survivors compacted (1 atomic/block) + survivor-only reset of next nm buffer.
template<int R>
__global__ __launch_bounds__(256)
void k_mpick(const ulonglong2* __restrict__ fin, const u32* __restrict__ cntp,
             const u64* __restrict__ nm, u64* nmNext, u8* matched,
             ulonglong2* fout, u32* cntOut, ulonglong2* sortbuf, u32* scalars) {
  __shared__ u32 wb[4];
  __shared__ u32 bbase;
  u32 cnt = *cntp;
  int tx = threadIdx.x, lane = tx & 63, wid = tx >> 6;
  for (u32 base = blockIdx.x * 256; base < cnt; base += gridDim.x * 256) {
    u32 gid = base + tx;
    ulonglong2 t = make_ulonglong2(0ull, 0ull);
    int s = 0, d = 0;
    bool pk = false, surv = false;
    if (gid < cnt) {
      t = fin[gid];
      s = (int)(t.y >> 32); d = (int)(u32)t.y;
      if (!(matched[s] | matched[d])) {
        if (nm[s] == t.x && nm[d] == t.x) pk = true; else surv = true;
      }
    }
    // picks: wave-aggregated append (order fixed by later sort)
    u64 pm = __ballot(pk);
    if (pm) {
      u32 pre = (u32)__popcll(pm & ((1ull << lane) - 1ull));
      int ldr = __ffsll((long long)pm) - 1;
      u32 pb = 0;
      if (lane == ldr) pb = atomicAdd(&scalars[0], (u32)__popcll(pm));
      pb = __shfl(pb, ldr);
      if (pk) {
        matched[s] = 1; matched[d] = 1;
        sortbuf[pb + pre] = t;
      }
    }
    // survivors: block-aggregated compaction + nmNext reset (exactly the
    // nodes the next round can touch)
    u64 sm = __ballot(surv);
    if (lane == 0) wb[wid] = (u32)__popcll(sm);
    __syncthreads();
    if (tx == 0) {
      u32 tt = wb[0] + wb[1] + wb[2] + wb[3];
      bbase = tt ? atomicAdd(cntOut, tt) : 0u;
    }
    __syncthreads();
    if (surv) {
      u32 woff = 0;
      for (int w = 0; w < wid; w++) woff += wb[w];
      u32 pre = (u32)__popcll(sm & ((1ull << lane) - 1ull));
      fout[bbase + woff + pre] = t;
      nmNext[s] = ~0ull;
      nmNext[d] = ~0ull;
    }
    __syncthreads();
  }
}

// single-block fence-free finish. The only cross-path hazard is nm (written by
// L2 atomics, read otherwise through L1) -> read it via atomicAdd(p,0) which
// goes to L2. Everything else is same-L1 plain ops ordered by __syncthreads.
__global__ __launch_bounds__(1024)
void k_mfinish(ulonglong2* fA, ulonglong2* fB, u8* matched, u64* nm,
               ulonglong2* sortbuf, const u32* __restrict__ cntp, u32* scalars) {
  __shared__ u32 sh_cnt;
  u32 cnt = *cntp;
  int tx = threadIdx.x;
  ulonglong2* fin = fA; ulonglong2* fout = fB;
  while (cnt > 0) {
    for (u32 i = tx; i < cnt; i += 1024) {
      u64 p = fin[i].y;
      nm[p >> 32] = ~0ull; nm[(u32)p] = ~0ull;
    }
    if (tx == 0) sh_cnt = 0;
    __syncthreads();
    for (u32 i = tx; i < cnt; i += 1024) {
      ulonglong2 t = fin[i];
      int s = (int)(t.y >> 32), d = (int)(u32)t.y;
      if (matched[s] | matched[d]) continue;
      atomicMin(&nm[s], t.x);
      if (d != s) atomicMin(&nm[d], t.x);
    }
    __syncthreads();
    for (u32 i = tx; i < cnt; i += 1024) {
      ulonglong2 t = fin[i];
      int s = (int)(t.y >> 32), d = (int)(u32)t.y;
      if (matched[s] | matched[d]) continue;
      u64 a = atomicAdd(&nm[s], 0ull);            // atomic read (L2-coherent)
      u64 b = (d == s) ? a : atomicAdd(&nm[d], 0ull);
      if (a == t.x && b == t.x) {
        matched[s] = 1; matched[d] = 1;
        u32 o = atomicAdd(&scalars[0], 1u);
        sortbuf[o] = t;
      } else {
        u32 o = atomicAdd(&sh_cnt, 1u);
        fout[o] = t;
      }
    }
    __syncthreads();
    cnt = sh_cnt;
    ulonglong2* tmp = fin; fin = fout; fout = tmp;
    __syncthreads();
  }
}

// ---- bitonic sort of SORTN {key,sd} pairs by .x, as plain launches ----
__global__ __launch_bounds__(256)
void k_sort1(ulonglong2* buf) {
  __shared__ ulonglong2 t[STILE];
  const int base = blockIdx.x * STILE;
  for (int i = threadIdx.x; i < STILE; i += 256) t[i] = buf[base + i];
  __syncthreads();
  for (int k = 2; k <= STILE; k <<= 1) {
    for (int j = k >> 1; j > 0; j >>= 1) {
      for (int i = threadIdx.x; i < STILE; i += 256) {
        int p = i ^ j;
        if (p > i) {
          bool dir = (((base + i) & k) == 0);
          ulonglong2 a = t[i], c = t[p];
          if ((a.x > c.x) == dir) { t[i] = c; t[p] = a; }
        }
      }
      __syncthreads();
    }
  }
  for (int i = threadIdx.x; i < STILE; i += 256) buf[base + i] = t[i];
}

__global__ __launch_bounds__(256)
void k_gpass(ulonglong2* buf, int j, int k) {
  int i = blockIdx.x * 256 + threadIdx.x;
  int p = i ^ j;
  if (p > i && p < SORTN) {
    bool dir = ((i & k) == 0);
    ulonglong2 a = buf[i], c = buf[p];
    if ((a.x > c.x) == dir) { buf[i] = c; buf[p] = a; }
  }
}

__global__ __launch_bounds__(256)
void k_sortl(ulonglong2* buf, int k) {
  __shared__ ulonglong2 t[STILE];
  const int base = blockIdx.x * STILE;
  const bool dir = ((base & k) == 0);   // uniform per tile (k > STILE)
  for (int i = threadIdx.x; i < STILE; i += 256) t[i] = buf[base + i];
  __syncthreads();
  for (int j = STILE >> 1; j > 0; j >>= 1) {
    for (int i = threadIdx.x; i < STILE; i += 256) {
      int p = i ^ j;
      if (p > i) {
        ulonglong2 a = t[i], c = t[p];
        if ((a.x > c.x) == dir) { t[i] = c; t[p] = a; }
      }
    }
    __syncthreads();
  }
  for (int i = threadIdx.x; i < STILE; i += 256) buf[base + i] = t[i];
}

// sorted position i == cluster id; score recovered bit-exactly from the key
__global__ __launch_bounds__(256)
void k_assign(const ulonglong2* __restrict__ buf,
              int* cluster, int* memA, int* memB, float* scoreC,
              const u32* __restrict__ scalars) {
  int i = blockIdx.x * blockDim.x + threadIdx.x;
  if (i >= (int)scalars[0]) return;
  ulonglong2 t = buf[i];
  int s = (int)(t.y >> 32), d = (int)(u32)t.y;
  cluster[s] = i; cluster[d] = i;
  scoreC[i] = inv_ordf(~(u32)(t.x >> 32));
  memA[i] = s;
  memB[i] = (s == d) ? -1 : d;   // self-loop: single member
}

// exclusive scan of unmatched nodes -> trailing singleton cluster ids
__global__ __launch_bounds__(256)
void k_scan1(const u8* __restrict__ matched, u32* partials, int N) {
  __shared__ u32 sh[256];
  int b = blockIdx.x, tx = threadIdx.x;
  int v0 = b * 1024 + tx * 4;
  u32 c = 0;
  #pragma unroll
  for (int q = 0; q < 4; q++) { int v = v0 + q; if (v < N && !matched[v]) c++; }
  sh[tx] = c; __syncthreads();
  for (int s = 128; s > 0; s >>= 1) { if (tx < s) sh[tx] += sh[tx + s]; __syncthreads(); }
  if (tx == 0) partials[b] = sh[0];
}

__global__ void k_scan2(const u32* partials, u32* partials2, u32* scalars, int NB) {
  if (blockIdx.x == 0 && threadIdx.x == 0) {
    u32 run = 0;
    for (int i = 0; i < NB; i++) { partials2[i] = run; run += partials[i]; }
    scalars[1] = run;                 // total unmatched
    scalars[2] = scalars[0] + run;    // num_clusters
  }
}

__global__ __launch_bounds__(256)
void k_scan3(const u8* __restrict__ matched, const u32* __restrict__ partials2,
             const u32* __restrict__ scalars, int* cluster, int* memA, int* memB, int N) {
  __shared__ u32 sh[256];
  int b = blockIdx.x, tx = threadIdx.x;
  int v0 = b * 1024 + tx * 4;
  u32 f[4]; u32 c = 0;
  #pragma unroll
  for (int q = 0; q < 4; q++) { int v = v0 + q; f[q] = (v < N && !matched[v]); c += f[q]; }
  sh[tx] = c; __syncthreads();
  for (int s = 1; s < 256; s <<= 1) {      // Hillis-Steele inclusive scan
    u32 x = sh[tx];
    u32 y = (tx >= s) ? sh[tx - s] : 0;
    __syncthreads();
    sh[tx] = x + y;
    __syncthreads();
  }
  u32 base = scalars[0] + partials2[b] + (sh[tx] - c);
  #pragma unroll
  for (int q = 0; q < 4; q++) {
    if (f[q]) {
      int v = v0 + q;
      int cc = (int)base++;
      cluster[v] = cc; memA[cc] = v; memB[cc] = -1;
    }
  }
}

// new_x: wave per output row; <=2 members per cluster; zero tail rows
__global__ __launch_bounds__(256)
void k_newx(const float4* __restrict__ x4, const int* __restrict__ memA,
            const int* __restrict__ memB, const float* __restrict__ scoreC,
            const u32* __restrict__ scalars, float4* __restrict__ out4, int N) {
  int gt = blockIdx.x * blockDim.x + threadIdx.x;
  int w = gt >> 6, lane = gt & 63;
  if (w >= N) return;
  int nc = (int)scalars[2];
  float4 o;
  if (w < nc) {
    int a = memA[w], b = memB[w];
    float s = scoreC[w];
    float4 va = x4[(size_t)a * 64 + lane];
    float ox = va.x, oy = va.y, oz = va.z, ow = va.w;
    if (b >= 0) {
      float4 vb = x4[(size_t)b * 64 + lane];
      ox += vb.x; oy += vb.y; oz += vb.z; ow += vb.w;
    }
    o = make_float4(ox * s, oy * s, oz * s, ow * s);
  } else {
    o = make_float4(0.f, 0.f, 0.f, 0.f);
  }
  out4[(size_t)w * 64 + lane] = o;
}

__global__ __launch_bounds__(256)
void k_remap(const int* __restrict__ ei, const int* __restrict__ cluster,
             float* __restrict__ outE, int twoE) {
  int i = blockIdx.x * blockDim.x + threadIdx.x;
  if (i < twoE) outE[i] = (float)cluster[ei[i]];
}

__global__ __launch_bounds__(256)
void k_tail(float* __restrict__ outB, const u32* __restrict__ scalars, int N) {
  int i = blockIdx.x * blockDim.x + threadIdx.x;
  if (i < N) outB[i] = 0.0f;                  // batch is all zeros
  if (i == 0) outB[N] = (float)scalars[2];    // num_clusters
}

// compile-time unrolled round launcher (distinct kernel symbols per round)
template<int R>
static void launch_rounds(ulonglong2* frontA, ulonglong2* frontB, u64* node_min,
                          u8* matched, ulonglong2* sortbuf, u32* fcnt, u32* scalars,
                          int N, int NB_E, hipStream_t stream) {
  if constexpr (R < NROUNDS) {
    ulonglong2* fin  = (R & 1) ? frontB : frontA;
    ulonglong2* fout = (R & 1) ? frontA : frontB;
    u64* nm  = node_min + (size_t)(R & 1) * N;
    u64* nmN = node_min + (size_t)((R & 1) ^ 1) * N;
    int nbr = NB_E >> R; if (nbr < 256) nbr = 256;
    k_mmin<R><<<nbr, 256, 0, stream>>>(fin, fcnt + R, matched, nm);
    k_mpick<R><<<nbr, 256, 0, stream>>>(fin, fcnt + R, nm, nmN, matched,
                                        fout, fcnt + R + 1, sortbuf, scalars);
    launch_rounds<R + 1>(frontA, frontB, node_min, matched, sortbuf, fcnt, scalars,
                         N, NB_E, stream);
  }
}

extern "C" void kernel_launch(void* const* d_in, const int* in_sizes, int n_in,
                              void* d_out, int out_size, void* d_ws, size_t ws_size,
                              hipStream_t stream) {
  const float* x    = (const float*)d_in[0];
  const int*   ei   = (const int*)d_in[1];
  const float* W    = (const float*)d_in[3];
  const float* bvec = (const float*)d_in[4];
  int N = in_sizes[2];
  int E = in_sizes[1] / 2;

  // workspace carve-out (~57 MB)
  char* p = (char*)d_ws;
  auto alloc = [&](size_t bytes) { char* r = p; p += (bytes + 255) & ~(size_t)255; return r; };
  float*      s_src    = (float*)alloc((size_t)N * 4);
  float*      s_dst    = (float*)alloc((size_t)N * 4);
  u32*        m_ord    = (u32*)alloc((size_t)N * 4);
  double*     ssum     = (double*)alloc((size_t)N * 8);
  ulonglong2* frontA   = (ulonglong2*)alloc((size_t)E * 16);
  ulonglong2* frontB   = (ulonglong2*)alloc((size_t)E * 16);
  u8*         matched  = (u8*)alloc((size_t)N);
  u64*        node_min = (u64*)alloc((size_t)2 * N * 8);
  ulonglong2* sortbuf  = (ulonglong2*)alloc((size_t)SORTN * 16);
  int*        cluster  = (int*)alloc((size_t)N * 4);
  int*        memA     = (int*)alloc((size_t)N * 4);
  int*        memB     = (int*)alloc((size_t)N * 4);
  float*      scoreC   = (float*)alloc((size_t)N * 4);
  u32*        fcnt     = (u32*)alloc(1024);
  u32*        partials = (u32*)alloc(4096);
  u32*        partials2= (u32*)alloc(4096);
  u32*        scalars  = (u32*)alloc(256);
  (void)ws_size; (void)out_size; (void)n_in;

  const int* srcp = ei;
  const int* dstp = ei + E;
  float* out  = (float*)d_out;
  float* outX = out;
  float* outE = out + (size_t)N * 256;
  float* outB = outE + (size_t)2 * E;

  int NB_E = (E + 255) / 256;
  int cover = (N > SORTN) ? N : SORTN;
  k_init<<<(cover + 255) / 256, 256, 0, stream>>>(m_ord, ssum, matched, node_min,
                                                  scoreC, sortbuf, fcnt, scalars, N, E);
  k_dots<<<((size_t)N * 64 + 255) / 256, 256, 0, stream>>>(
      (const float4*)x, (const float4*)W, s_src, s_dst, N);
  k_max<<<NB_E, 256, 0, stream>>>(srcp, dstp, s_src, s_dst, bvec, m_ord, E);
  k_expsum<<<NB_E, 256, 0, stream>>>(srcp, dstp, s_src, s_dst, bvec, m_ord, ssum, E);
  k_scorekey<<<NB_E, 256, 0, stream>>>(srcp, dstp, s_src, s_dst, bvec, m_ord, ssum,
                                       frontA, E);

  launch_rounds<0>(frontA, frontB, node_min, matched, sortbuf, fcnt, scalars,
                   N, NB_E, stream);
  // NROUNDS even -> final survivors in frontA; nm buffer 0 gets reset in-kernel
  k_mfinish<<<1, 1024, 0, stream>>>(frontA, frontB, matched, node_min, sortbuf,
                                    fcnt + NROUNDS, scalars);

  // sort chosen edges (bitonic over SORTN, plain launches)
  k_sort1<<<SORTN / STILE, 256, 0, stream>>>(sortbuf);
  for (int k = STILE << 1; k <= SORTN; k <<= 1) {
    for (int j = k >> 1; j >= STILE; j >>= 1)
      k_gpass<<<SORTN / 256, 256, 0, stream>>>(sortbuf, j, k);
    k_sortl<<<SORTN / STILE, 256, 0, stream>>>(sortbuf, k);
  }

  k_assign<<<SORTN / 256, 256, 0, stream>>>(sortbuf, cluster, memA, memB, scoreC, scalars);
  int NB = (N + 1023) / 1024;
  k_scan1<<<NB, 256, 0, stream>>>(matched, partials, N);
  k_scan2<<<1, 64, 0, stream>>>(partials, partials2, scalars, NB);
  k_scan3<<<NB, 256, 0, stream>>>(matched, partials2, scalars, cluster, memA, memB, N);

  k_newx<<<((size_t)N * 64 + 255) / 256, 256, 0, stream>>>(
      (const float4*)x, memA, memB, scoreC, scalars, (float4*)outX, N);
  k_remap<<<(2 * E + 255) / 256, 256, 0, stream>>>(ei, cluster, outE, 2 * E);
  k_tail<<<(N + 255) / 256, 256, 0, stream>>>(outB, scalars, N);
}